// Round 5
// baseline (1954.671 us; speedup 1.0000x reference)
//
#include <hip/hip_runtime.h>

#define CDIM 128
#define KOFF 4
#define EPS 1e-4f
#define SCAN_CHUNK 2048   // 256 threads * 8 elems
#define ROWS 16           // output rows per block

typedef __attribute__((ext_vector_type(8))) short bf16x8;
typedef __attribute__((ext_vector_type(4))) float f32x4;

__device__ __forceinline__ unsigned short f2bf(float f) {
    unsigned int u = __builtin_bit_cast(unsigned int, f);
    u += 0x7fffu + ((u >> 16) & 1u);          // round-to-nearest-even
    return (unsigned short)(u >> 16);
}
__device__ __forceinline__ float bf2f(unsigned short h) {
    unsigned int u = ((unsigned int)h) << 16;
    return __builtin_bit_cast(float, u);
}

// ---------------------------------------------------------------------------
// W convert+transpose: Wt[k][cout][cin] = bf16(W[k][cin][cout])
// ---------------------------------------------------------------------------
__global__ __launch_bounds__(256) void wconv_kernel(
    const float* __restrict__ W1, const float* __restrict__ W2,
    short* __restrict__ W1t, short* __restrict__ W2t)
{
    int idx = blockIdx.x * 256 + threadIdx.x;       // [k][co][ci]
    if (idx >= KOFF * CDIM * CDIM) return;
    int ci = idx & (CDIM - 1);
    int co = (idx >> 7) & (CDIM - 1);
    int k  = idx >> 14;
    size_t src = (size_t)k * CDIM * CDIM + (size_t)ci * CDIM + co;
    W1t[idx] = (short)f2bf(W1[src]);
    W2t[idx] = (short)f2bf(W2[src]);
}

// ---------------------------------------------------------------------------
// Rulebook keyed by bucket = j*4 + k  (block-contiguous entry ranges).
// Entry = src | (jloc<<19) | (k<<23),  jloc = j & 15.
// ---------------------------------------------------------------------------
__global__ __launch_bounds__(256) void count_kernel(
    const int* __restrict__ out_idx, const int* __restrict__ mask,
    int* __restrict__ cnt, int n)
{
    int i = blockIdx.x * 256 + threadIdx.x;
    if (i >= n) return;
    int k = blockIdx.y;
    size_t s = (size_t)k * n + i;
    if (mask[s]) atomicAdd(&cnt[(size_t)out_idx[s] * KOFF + k], 1);
}

__global__ __launch_bounds__(256) void scan_p1(
    const int* __restrict__ in, int* __restrict__ bsum, int L)
{
    __shared__ int red[256];
    int base = blockIdx.x * SCAN_CHUNK;
    int s = 0;
    #pragma unroll
    for (int u = 0; u < 8; ++u) {
        int i = base + u * 256 + threadIdx.x;
        if (i < L) s += in[i];
    }
    red[threadIdx.x] = s;
    __syncthreads();
    for (int d = 128; d > 0; d >>= 1) {
        if (threadIdx.x < d) red[threadIdx.x] += red[threadIdx.x + d];
        __syncthreads();
    }
    if (threadIdx.x == 0) bsum[blockIdx.x] = red[0];
}

__global__ __launch_bounds__(1024) void scan_p2(int* __restrict__ bsum, int NB)
{
    __shared__ int s[1024];
    int t = threadIdx.x;
    s[t] = (t < NB) ? bsum[t] : 0;
    __syncthreads();
    for (int d = 1; d < 1024; d <<= 1) {
        int x = s[t];
        if (t >= d) x += s[t - d];
        __syncthreads();
        s[t] = x;
        __syncthreads();
    }
    if (t < NB) bsum[t] = (t == 0) ? 0 : s[t - 1];   // exclusive
}

__global__ __launch_bounds__(256) void scan_p3(
    const int* __restrict__ in, const int* __restrict__ bsum,
    int* __restrict__ out, int L)
{
    __shared__ int ts[256];
    int t = threadIdx.x;
    int base = blockIdx.x * SCAN_CHUNK + t * 8;
    int v[8]; int s = 0;
    #pragma unroll
    for (int u = 0; u < 8; ++u) {
        int i = base + u;
        v[u] = (i < L) ? in[i] : 0;
        s += v[u];
    }
    ts[t] = s;
    __syncthreads();
    for (int d = 1; d < 256; d <<= 1) {
        int x = ts[t];
        if (t >= d) x += ts[t - d];
        __syncthreads();
        ts[t] = x;
        __syncthreads();
    }
    int pre = bsum[blockIdx.x] + ((t == 0) ? 0 : ts[t - 1]);
    #pragma unroll
    for (int u = 0; u < 8; ++u) {
        int i = base + u;
        if (i < L) { out[i] = pre; pre += v[u]; }
    }
}

__global__ __launch_bounds__(256) void fill_kernel(
    const int* __restrict__ out_idx, const int* __restrict__ in_idx,
    const int* __restrict__ mask, int* __restrict__ off,
    int* __restrict__ ent, int n)
{
    int i = blockIdx.x * 256 + threadIdx.x;
    if (i >= n) return;
    int k = blockIdx.y;
    size_t s = (size_t)k * n + i;
    if (mask[s]) {
        int j = out_idx[s];
        int pos = atomicAdd(&off[(size_t)j * KOFF + k], 1);
        ent[pos] = in_idx[s] | ((j & (ROWS - 1)) << 19) | (k << 23);
    }
}
// post-fill: off[b] = END of bucket b; start = (b==0) ? 0 : off[b-1]

// ---------------------------------------------------------------------------
// Conv: block owns 16 output rows; its entries (all k) are ent[e0..e1).
//  p1: entry-parallel gather (32 lanes/entry, coalesced) -> ds_add into
//      swizzled f32 tile Af[16][512]   (chunk pos = ch ^ (row&7))
//  p2: f32 -> bf16 in place (regs + barrier), Ab aliases Af
//  p3: dense 16x512 @ 512x128 MFMA (W frags from L1/L2)
//  p4: fused BN epilogue.  EPI=0: bf16(relu(bn(.)))  EPI=1: bn(.)+feat f32
// ---------------------------------------------------------------------------
template <int EPI>
__global__ __launch_bounds__(256) void conv_csr_kernel(
    const void* __restrict__ Xv, const short* __restrict__ Wt,
    const int* __restrict__ off, const int* __restrict__ ent,
    const float* __restrict__ gamma, const float* __restrict__ beta,
    const float* __restrict__ mean, const float* __restrict__ var,
    const float* __restrict__ feat, void* __restrict__ Yv, int n)
{
    const int j0 = blockIdx.x * ROWS;
    const int t  = threadIdx.x;

    __shared__ alignas(16) float Af[ROWS * 512];     // 32 KB f32 acc tile
    __shared__ alignas(16) float s_scale[CDIM], s_shift[CDIM];
    short* Ab = (short*)Af;           // bf16 tile aliases words 0..4095
    float* Ot = Af + 4096;            // f32 out tile, words 4096..6143 (no alias w/ Ab)

    if (t < CDIM) {
        float sc = gamma[t] * rsqrtf(var[t] + EPS);
        s_scale[t] = sc;
        s_shift[t] = beta[t] - mean[t] * sc;
    }
    {
        float4 z = make_float4(0.f, 0.f, 0.f, 0.f);
        #pragma unroll
        for (int u = 0; u < 8; ++u) ((float4*)Af)[u * 256 + t] = z;
    }
    __syncthreads();

    const int jend = min(j0 + ROWS, n);
    const int e0 = (j0 == 0) ? 0 : off[(size_t)j0 * KOFF - 1];
    const int e1 = off[(size_t)jend * KOFF - 1];

    // ---- p1: gather. group (t>>5) handles 4 entries/batch, 32 lanes/entry ----
    const int grp = t >> 5;
    const int gl  = t & 31;
    for (int c0 = e0; c0 < e1; c0 += 32) {
        int base = c0 + grp * 4;
        int ev[4];
        #pragma unroll
        for (int u = 0; u < 4; ++u) {
            int e = base + u;
            ev[u] = (e < e1) ? ent[e] : -1;
        }
        float4 vr[4];
        #pragma unroll
        for (int u = 0; u < 4; ++u) {
            if (ev[u] >= 0) {
                int src = ev[u] & 0x7FFFF;
                if (EPI == 0) {
                    vr[u] = *((const float4*)Xv + (size_t)src * 32 + gl);
                } else {
                    short4 v = *((const short4*)((const short*)Xv + (size_t)src * CDIM) + gl);
                    vr[u] = make_float4(bf2f((unsigned short)v.x), bf2f((unsigned short)v.y),
                                        bf2f((unsigned short)v.z), bf2f((unsigned short)v.w));
                }
            }
        }
        #pragma unroll
        for (int u = 0; u < 4; ++u) {
            if (ev[u] >= 0) {
                int jl = (ev[u] >> 19) & (ROWS - 1);
                int k  = (ev[u] >> 23) & 3;
                int ch = k * 32 + gl;                 // f32 chunk 0..127
                float* dst = Af + jl * 512 + ((ch ^ (jl & 7)) << 2);
                atomicAdd(dst + 0, vr[u].x);
                atomicAdd(dst + 1, vr[u].y);
                atomicAdd(dst + 2, vr[u].z);
                atomicAdd(dst + 3, vr[u].w);
            }
        }
    }
    __syncthreads();

    // ---- p2: f32 -> bf16 in place. thread: row r = t&15, chunks (t>>4)*4+u ----
    {
        const int r = t & 15;
        float4 cv[8];
        #pragma unroll
        for (int u = 0; u < 4; ++u) {
            int ch = ((t >> 4) * 4 + u) * 2;
            cv[u * 2 + 0] = *(const float4*)(Af + r * 512 + (((ch + 0) ^ (r & 7)) << 2));
            cv[u * 2 + 1] = *(const float4*)(Af + r * 512 + (((ch + 1) ^ (r & 7)) << 2));
        }
        __syncthreads();
        #pragma unroll
        for (int u = 0; u < 4; ++u) {
            int cb = (t >> 4) * 4 + u;
            float4 a = cv[u * 2], b = cv[u * 2 + 1];
            bf16x8 v;
            v[0] = (short)f2bf(a.x); v[1] = (short)f2bf(a.y);
            v[2] = (short)f2bf(a.z); v[3] = (short)f2bf(a.w);
            v[4] = (short)f2bf(b.x); v[5] = (short)f2bf(b.y);
            v[6] = (short)f2bf(b.z); v[7] = (short)f2bf(b.w);
            *(bf16x8*)(Ab + r * 512 + ((cb ^ (r & 7)) << 3)) = v;
        }
    }
    __syncthreads();

    // ---- p3: MFMA. wave w: couts w*32..+31, 16 K-steps ----
    const int w    = t >> 6;
    const int lane = t & 63;
    const int lrow = lane & 15;
    const int g    = lane >> 4;

    f32x4 acc[2];
    acc[0] = (f32x4){0.f, 0.f, 0.f, 0.f};
    acc[1] = (f32x4){0.f, 0.f, 0.f, 0.f};

    #pragma unroll
    for (int ks = 0; ks < 16; ++ks) {
        int k  = ks >> 2;
        int kk = ks & 3;
        const short* Wk = Wt + (size_t)k * CDIM * CDIM + kk * 32 + g * 8;
        bf16x8 b0 = *(const bf16x8*)(Wk + (w * 32 + lrow) * CDIM);
        bf16x8 b1 = *(const bf16x8*)(Wk + (w * 32 + 16 + lrow) * CDIM);
        int cb = ks * 4 + g;
        bf16x8 a = *(const bf16x8*)(Ab + lrow * 512 + ((cb ^ (lrow & 7)) << 3));
        acc[0] = __builtin_amdgcn_mfma_f32_16x16x32_bf16(a, b0, acc[0], 0, 0, 0);
        acc[1] = __builtin_amdgcn_mfma_f32_16x16x32_bf16(a, b1, acc[1], 0, 0, 0);
    }

    // ---- acc -> Ot (disjoint from Ab; no barrier needed before writes) ----
    #pragma unroll
    for (int nt = 0; nt < 2; ++nt)
        #pragma unroll
        for (int j = 0; j < 4; ++j)
            Ot[(g * 4 + j) * CDIM + w * 32 + nt * 16 + lrow] = acc[nt][j];
    __syncthreads();

    // ---- p4: fused BN epilogue ----
    #pragma unroll
    for (int u = 0; u < 2; ++u) {
        int idx = u * 256 + t;          // 0..511 = 16 rows * 32 float4
        int row = idx >> 5, c4 = idx & 31;
        int grow = j0 + row;
        if (grow < n) {
            float4 x  = ((const float4*)Ot)[idx];
            float4 sc = ((const float4*)s_scale)[c4];
            float4 sh = ((const float4*)s_shift)[c4];
            size_t go = (size_t)grow * 32 + c4;
            if (EPI == 0) {
                ushort4 o;
                o.x = f2bf(fmaxf(x.x * sc.x + sh.x, 0.f));
                o.y = f2bf(fmaxf(x.y * sc.y + sh.y, 0.f));
                o.z = f2bf(fmaxf(x.z * sc.z + sh.z, 0.f));
                o.w = f2bf(fmaxf(x.w * sc.w + sh.w, 0.f));
                ((ushort4*)Yv)[go] = o;
            } else {
                float4 f = ((const float4*)feat)[go];
                float4 r;
                r.x = x.x * sc.x + sh.x + f.x;
                r.y = x.y * sc.y + sh.y + f.y;
                r.z = x.z * sc.z + sh.z + f.z;
                r.w = x.w * sc.w + sh.w + f.w;
                ((float4*)Yv)[go] = r;
            }
        }
    }
}

extern "C" void kernel_launch(void* const* d_in, const int* in_sizes, int n_in,
                              void* d_out, int out_size, void* d_ws, size_t ws_size,
                              hipStream_t stream)
{
    const float* feat   = (const float*)d_in[0];
    const float* W1     = (const float*)d_in[1];
    const float* W2     = (const float*)d_in[2];
    const float* gamma1 = (const float*)d_in[3];
    const float* beta1  = (const float*)d_in[4];
    const float* mean1  = (const float*)d_in[5];
    const float* var1   = (const float*)d_in[6];
    const float* gamma2 = (const float*)d_in[7];
    const float* beta2  = (const float*)d_in[8];
    const float* mean2  = (const float*)d_in[9];
    const float* var2   = (const float*)d_in[10];
    const int* in_idx   = (const int*)d_in[11];
    const int* out_idx  = (const int*)d_in[12];
    const int* mask     = (const int*)d_in[13];

    const int n  = in_sizes[0] / CDIM;     // 500000 (< 2^19 for entry packing)
    const int KN = KOFF * n;
    const int L  = KN + 1;
    const int NB = (L + SCAN_CHUNK - 1) / SCAN_CHUNK;   // 977 <= 1024

    auto alignup = [](size_t x) { return (x + 255) & ~(size_t)255; };
    char* p = (char*)d_ws;
    int*   cnt  = (int*)p;   p += alignup((size_t)L * 4);
    int*   off  = (int*)p;   p += alignup((size_t)L * 4);
    int*   bsum = (int*)p;   p += alignup(4096 * 4);
    int*   ent  = (int*)p;   p += alignup((size_t)KN * 4);
    short* W1t  = (short*)p; p += alignup((size_t)KOFF * CDIM * CDIM * 2);
    short* W2t  = (short*)p; p += alignup((size_t)KOFF * CDIM * CDIM * 2);
    short* h1b  = (short*)p;                         // n*128 bf16 = 128 MB

    // rulebook (bucket = j*4 + k)
    hipMemsetAsync(cnt, 0, (size_t)L * 4, stream);
    wconv_kernel<<<(KOFF * CDIM * CDIM + 255) / 256, 256, 0, stream>>>(W1, W2, W1t, W2t);
    dim3 cg((n + 255) / 256, KOFF);
    count_kernel<<<cg, 256, 0, stream>>>(out_idx, mask, cnt, n);
    scan_p1<<<NB, 256, 0, stream>>>(cnt, bsum, L);
    scan_p2<<<1, 1024, 0, stream>>>(bsum, NB);
    scan_p3<<<NB, 256, 0, stream>>>(cnt, bsum, off, L);
    fill_kernel<<<cg, 256, 0, stream>>>(out_idx, in_idx, mask, off, ent, n);

    // fused convs
    const int nblk = (n + ROWS - 1) / ROWS;
    conv_csr_kernel<0><<<nblk, 256, 0, stream>>>(
        feat, W1t, off, ent, gamma1, beta1, mean1, var1, nullptr, h1b, n);
    conv_csr_kernel<1><<<nblk, 256, 0, stream>>>(
        h1b, W2t, off, ent, gamma2, beta2, mean2, var2, feat, d_out, n);
}

// Round 6
// 974.051 us; speedup vs baseline: 2.0067x; 2.0067x over previous
//
#include <hip/hip_runtime.h>

#define CDIM 128
#define KOFF 4
#define EPS 1e-4f
#define SCAN_CHUNK 2048   // 256 threads * 8 elems
#define ROWS 64           // output rows per block

typedef __attribute__((ext_vector_type(8))) short bf16x8;
typedef __attribute__((ext_vector_type(4))) float f32x4;

__device__ __forceinline__ unsigned short f2bf(float f) {
    unsigned int u = __builtin_bit_cast(unsigned int, f);
    u += 0x7fffu + ((u >> 16) & 1u);          // round-to-nearest-even
    return (unsigned short)(u >> 16);
}
__device__ __forceinline__ float bf2f(unsigned short h) {
    unsigned int u = ((unsigned int)h) << 16;
    return __builtin_bit_cast(float, u);
}

// ---------------------------------------------------------------------------
// W convert+transpose: Wt[k][cout][cin] = bf16(W[k][cin][cout])
// ---------------------------------------------------------------------------
__global__ __launch_bounds__(256) void wconv_kernel(
    const float* __restrict__ W1, const float* __restrict__ W2,
    short* __restrict__ W1t, short* __restrict__ W2t)
{
    int idx = blockIdx.x * 256 + threadIdx.x;       // [k][co][ci]
    if (idx >= KOFF * CDIM * CDIM) return;
    int ci = idx & (CDIM - 1);
    int co = (idx >> 7) & (CDIM - 1);
    int k  = idx >> 14;
    size_t src = (size_t)k * CDIM * CDIM + (size_t)ci * CDIM + co;
    W1t[idx] = (short)f2bf(W1[src]);
    W2t[idx] = (short)f2bf(W2[src]);
}

// ---------------------------------------------------------------------------
// Rulebook keyed by bucket = j*4 + k (block-contiguous entry ranges).
// Entry = src | (jloc<<19) | (k<<25),  jloc = j & 63,  src < 2^19.
// ---------------------------------------------------------------------------
__global__ __launch_bounds__(256) void count_kernel(
    const int* __restrict__ out_idx, const int* __restrict__ mask,
    int* __restrict__ cnt, int n)
{
    int i = blockIdx.x * 256 + threadIdx.x;
    if (i >= n) return;
    int k = blockIdx.y;
    size_t s = (size_t)k * n + i;
    if (mask[s]) atomicAdd(&cnt[(size_t)out_idx[s] * KOFF + k], 1);
}

__global__ __launch_bounds__(256) void scan_p1(
    const int* __restrict__ in, int* __restrict__ bsum, int L)
{
    __shared__ int red[256];
    int base = blockIdx.x * SCAN_CHUNK;
    int s = 0;
    #pragma unroll
    for (int u = 0; u < 8; ++u) {
        int i = base + u * 256 + threadIdx.x;
        if (i < L) s += in[i];
    }
    red[threadIdx.x] = s;
    __syncthreads();
    for (int d = 128; d > 0; d >>= 1) {
        if (threadIdx.x < d) red[threadIdx.x] += red[threadIdx.x + d];
        __syncthreads();
    }
    if (threadIdx.x == 0) bsum[blockIdx.x] = red[0];
}

__global__ __launch_bounds__(1024) void scan_p2(int* __restrict__ bsum, int NB)
{
    __shared__ int s[1024];
    int t = threadIdx.x;
    s[t] = (t < NB) ? bsum[t] : 0;
    __syncthreads();
    for (int d = 1; d < 1024; d <<= 1) {
        int x = s[t];
        if (t >= d) x += s[t - d];
        __syncthreads();
        s[t] = x;
        __syncthreads();
    }
    if (t < NB) bsum[t] = (t == 0) ? 0 : s[t - 1];   // exclusive
}

__global__ __launch_bounds__(256) void scan_p3(
    const int* __restrict__ in, const int* __restrict__ bsum,
    int* __restrict__ out, int L)
{
    __shared__ int ts[256];
    int t = threadIdx.x;
    int base = blockIdx.x * SCAN_CHUNK + t * 8;
    int v[8]; int s = 0;
    #pragma unroll
    for (int u = 0; u < 8; ++u) {
        int i = base + u;
        v[u] = (i < L) ? in[i] : 0;
        s += v[u];
    }
    ts[t] = s;
    __syncthreads();
    for (int d = 1; d < 256; d <<= 1) {
        int x = ts[t];
        if (t >= d) x += ts[t - d];
        __syncthreads();
        ts[t] = x;
        __syncthreads();
    }
    int pre = bsum[blockIdx.x] + ((t == 0) ? 0 : ts[t - 1]);
    #pragma unroll
    for (int u = 0; u < 8; ++u) {
        int i = base + u;
        if (i < L) { out[i] = pre; pre += v[u]; }
    }
}

__global__ __launch_bounds__(256) void fill_kernel(
    const int* __restrict__ out_idx, const int* __restrict__ in_idx,
    const int* __restrict__ mask, int* __restrict__ off,
    int* __restrict__ ent, int n)
{
    int i = blockIdx.x * 256 + threadIdx.x;
    if (i >= n) return;
    int k = blockIdx.y;
    size_t s = (size_t)k * n + i;
    if (mask[s]) {
        int j = out_idx[s];
        int pos = atomicAdd(&off[(size_t)j * KOFF + k], 1);
        ent[pos] = in_idx[s] | ((j & (ROWS - 1)) << 19) | (k << 25);
    }
}
// post-fill: off[b] = END of bucket b; start = (b==0) ? 0 : off[b-1]

// ---------------------------------------------------------------------------
// Conv: block owns 64 output rows.
//  p1: per-thread register bucket-sum (4 slices/thread, ranges hoisted)
//      -> swizzled bf16 A-tile [64][512] LDS   (chunk slot = c ^ (jl&7))
//  p2: dense 64x512 @ 512x128 MFMA (W frags from L2), acc in regs
//  p3: BN epilogue applied in registers, direct global store (no out-tile)
//  EPI=0: X=f32, out = bf16(relu(bn(.)))   EPI=1: X=bf16, out = bn(.)+feat f32
// ---------------------------------------------------------------------------
template <int EPI>
__global__ __launch_bounds__(256) void conv_csr_kernel(
    const void* __restrict__ Xv, const short* __restrict__ Wt,
    const int* __restrict__ off, const int* __restrict__ ent,
    const float* __restrict__ gamma, const float* __restrict__ beta,
    const float* __restrict__ mean, const float* __restrict__ var,
    const float* __restrict__ feat, void* __restrict__ Yv, int n)
{
    const int j0 = blockIdx.x * ROWS;
    const int t  = threadIdx.x;

    __shared__ alignas(16) short Ab[ROWS * 512];     // 64 KB bf16 A-tile
    __shared__ alignas(16) float s_scale[CDIM], s_shift[CDIM];

    if (t < CDIM) {
        float sc = gamma[t] * rsqrtf(var[t] + EPS);
        s_scale[t] = sc;
        s_shift[t] = beta[t] - mean[t] * sc;
    }

    // ---- p1: gather. slice s: jl = s>>4, k = (s>>2)&3, cg = s&3 ----
    int se0[4], se1[4];
    #pragma unroll
    for (int h = 0; h < 4; ++h) {
        int s  = t + h * 256;
        int jl = s >> 4;
        int k  = (s >> 2) & 3;
        int j  = j0 + jl;
        if (j < n) {
            size_t b = (size_t)j * KOFF + k;
            se0[h] = (b == 0) ? 0 : off[b - 1];
            se1[h] = off[b];
        } else { se0[h] = 0; se1[h] = 0; }
    }
    #pragma unroll
    for (int h = 0; h < 4; ++h) {
        int s  = t + h * 256;
        int jl = s >> 4;
        int k  = (s >> 2) & 3;
        int cg = s & 3;
        float acc[32];
        #pragma unroll
        for (int c = 0; c < 32; ++c) acc[c] = 0.f;
        for (int e = se0[h]; e < se1[h]; ++e) {
            int src = ent[e] & 0x7FFFF;
            if (EPI == 0) {
                const float4* xr = (const float4*)Xv + (size_t)src * 32 + cg * 8;
                #pragma unroll
                for (int u = 0; u < 8; ++u) {
                    float4 v = xr[u];
                    acc[u * 4 + 0] += v.x; acc[u * 4 + 1] += v.y;
                    acc[u * 4 + 2] += v.z; acc[u * 4 + 3] += v.w;
                }
            } else {
                const bf16x8* xr = (const bf16x8*)((const short*)Xv + (size_t)src * CDIM + cg * 32);
                #pragma unroll
                for (int u = 0; u < 4; ++u) {
                    bf16x8 v = xr[u];
                    #pragma unroll
                    for (int q = 0; q < 8; ++q)
                        acc[u * 8 + q] += bf2f((unsigned short)v[q]);
                }
            }
        }
        #pragma unroll
        for (int u = 0; u < 4; ++u) {
            int c = k * 16 + cg * 4 + u;             // chunk col 0..63
            bf16x8 v;
            #pragma unroll
            for (int q = 0; q < 8; ++q) v[q] = (short)f2bf(acc[u * 8 + q]);
            *(bf16x8*)(Ab + jl * 512 + ((c ^ (jl & 7)) << 3)) = v;
        }
    }
    __syncthreads();

    // ---- p2: MFMA. wave w: couts w*32..+31 (2 nt), all 64 rows (4 m) ----
    const int w    = t >> 6;
    const int lane = t & 63;
    const int lrow = lane & 15;
    const int g    = lane >> 4;

    f32x4 acc[4][2];
    #pragma unroll
    for (int m = 0; m < 4; ++m)
        #pragma unroll
        for (int nt = 0; nt < 2; ++nt) acc[m][nt] = (f32x4){0.f, 0.f, 0.f, 0.f};

    #pragma unroll
    for (int ks = 0; ks < 16; ++ks) {
        int k  = ks >> 2;
        int kk = ks & 3;
        const short* Wk = Wt + (size_t)k * CDIM * CDIM + kk * 32 + g * 8;
        bf16x8 b0 = *(const bf16x8*)(Wk + (w * 32 + lrow) * CDIM);
        bf16x8 b1 = *(const bf16x8*)(Wk + (w * 32 + 16 + lrow) * CDIM);
        int cb = ks * 4 + g;
        #pragma unroll
        for (int m = 0; m < 4; ++m) {
            int row = m * 16 + lrow;
            bf16x8 a = *(const bf16x8*)(Ab + row * 512 + ((cb ^ (row & 7)) << 3));
            acc[m][0] = __builtin_amdgcn_mfma_f32_16x16x32_bf16(a, b0, acc[m][0], 0, 0, 0);
            acc[m][1] = __builtin_amdgcn_mfma_f32_16x16x32_bf16(a, b1, acc[m][1], 0, 0, 0);
        }
    }

    // ---- p3: BN in registers, direct global store ----
    #pragma unroll
    for (int nt = 0; nt < 2; ++nt) {
        int col = w * 32 + nt * 16 + lrow;
        float sc = s_scale[col];
        float sh = s_shift[col];
        #pragma unroll
        for (int m = 0; m < 4; ++m) {
            #pragma unroll
            for (int jj = 0; jj < 4; ++jj) {
                int row = j0 + m * 16 + g * 4 + jj;
                if (row < n) {
                    float x = acc[m][nt][jj] * sc + sh;
                    size_t go = (size_t)row * CDIM + col;
                    if (EPI == 0) {
                        ((unsigned short*)Yv)[go] = f2bf(fmaxf(x, 0.f));
                    } else {
                        ((float*)Yv)[go] = x + feat[go];
                    }
                }
            }
        }
    }
}

extern "C" void kernel_launch(void* const* d_in, const int* in_sizes, int n_in,
                              void* d_out, int out_size, void* d_ws, size_t ws_size,
                              hipStream_t stream)
{
    const float* feat   = (const float*)d_in[0];
    const float* W1     = (const float*)d_in[1];
    const float* W2     = (const float*)d_in[2];
    const float* gamma1 = (const float*)d_in[3];
    const float* beta1  = (const float*)d_in[4];
    const float* mean1  = (const float*)d_in[5];
    const float* var1   = (const float*)d_in[6];
    const float* gamma2 = (const float*)d_in[7];
    const float* beta2  = (const float*)d_in[8];
    const float* mean2  = (const float*)d_in[9];
    const float* var2   = (const float*)d_in[10];
    const int* in_idx   = (const int*)d_in[11];
    const int* out_idx  = (const int*)d_in[12];
    const int* mask     = (const int*)d_in[13];

    const int n  = in_sizes[0] / CDIM;     // 500000 (< 2^19 for entry packing)
    const int KN = KOFF * n;
    const int L  = KN + 1;
    const int NB = (L + SCAN_CHUNK - 1) / SCAN_CHUNK;   // 977 <= 1024

    auto alignup = [](size_t x) { return (x + 255) & ~(size_t)255; };
    char* p = (char*)d_ws;
    int*   cnt  = (int*)p;   p += alignup((size_t)L * 4);
    int*   off  = (int*)p;   p += alignup((size_t)L * 4);
    int*   bsum = (int*)p;   p += alignup(4096 * 4);
    int*   ent  = (int*)p;   p += alignup((size_t)KN * 4);
    short* W1t  = (short*)p; p += alignup((size_t)KOFF * CDIM * CDIM * 2);
    short* W2t  = (short*)p; p += alignup((size_t)KOFF * CDIM * CDIM * 2);
    short* h1b  = (short*)p;                         // n*128 bf16 = 128 MB

    // rulebook (bucket = j*4 + k)
    hipMemsetAsync(cnt, 0, (size_t)L * 4, stream);
    wconv_kernel<<<(KOFF * CDIM * CDIM + 255) / 256, 256, 0, stream>>>(W1, W2, W1t, W2t);
    dim3 cg((n + 255) / 256, KOFF);
    count_kernel<<<cg, 256, 0, stream>>>(out_idx, mask, cnt, n);
    scan_p1<<<NB, 256, 0, stream>>>(cnt, bsum, L);
    scan_p2<<<1, 1024, 0, stream>>>(bsum, NB);
    scan_p3<<<NB, 256, 0, stream>>>(cnt, bsum, off, L);
    fill_kernel<<<cg, 256, 0, stream>>>(out_idx, in_idx, mask, off, ent, n);

    // fused convs
    const int nblk = (n + ROWS - 1) / ROWS;
    conv_csr_kernel<0><<<nblk, 256, 0, stream>>>(
        feat, W1t, off, ent, gamma1, beta1, mean1, var1, nullptr, h1b, n);
    conv_csr_kernel<1><<<nblk, 256, 0, stream>>>(
        h1b, W2t, off, ent, gamma2, beta2, mean2, var2, feat, d_out, n);
}

// Round 7
// 936.036 us; speedup vs baseline: 2.0882x; 1.0406x over previous
//
#include <hip/hip_runtime.h>

#define CDIM 128
#define KOFF 4
#define EPS 1e-4f
#define SCAN_CHUNK 2048   // 256 threads * 8 elems
#define ROWS 64           // output rows per block
#define NTHR 512

typedef __attribute__((ext_vector_type(8))) short bf16x8;
typedef __attribute__((ext_vector_type(4))) float f32x4;

__device__ __forceinline__ unsigned short f2bf(float f) {
    unsigned int u = __builtin_bit_cast(unsigned int, f);
    u += 0x7fffu + ((u >> 16) & 1u);          // round-to-nearest-even
    return (unsigned short)(u >> 16);
}
__device__ __forceinline__ float bf2f(unsigned short h) {
    unsigned int u = ((unsigned int)h) << 16;
    return __builtin_bit_cast(float, u);
}

// async global->LDS, 16B per lane; LDS dest = wave-uniform base + lane*16
__device__ __forceinline__ void gload_lds16(const void* g, void* l) {
    __builtin_amdgcn_global_load_lds(
        (const __attribute__((address_space(1))) void*)g,
        (__attribute__((address_space(3))) void*)l, 16, 0, 0);
}

// ---------------------------------------------------------------------------
// W convert+transpose: Wt[k][cout][cin] = bf16(W[k][cin][cout])
// ---------------------------------------------------------------------------
__global__ __launch_bounds__(256) void wconv_kernel(
    const float* __restrict__ W1, const float* __restrict__ W2,
    short* __restrict__ W1t, short* __restrict__ W2t)
{
    int idx = blockIdx.x * 256 + threadIdx.x;       // [k][co][ci]
    if (idx >= KOFF * CDIM * CDIM) return;
    int ci = idx & (CDIM - 1);
    int co = (idx >> 7) & (CDIM - 1);
    int k  = idx >> 14;
    size_t src = (size_t)k * CDIM * CDIM + (size_t)ci * CDIM + co;
    W1t[idx] = (short)f2bf(W1[src]);
    W2t[idx] = (short)f2bf(W2[src]);
}

// ---------------------------------------------------------------------------
// feat f32 -> bf16 streaming convert
// ---------------------------------------------------------------------------
__global__ __launch_bounds__(256) void cvt_kernel(
    const float* __restrict__ in, short* __restrict__ out, size_t total8)
{
    size_t stride = (size_t)gridDim.x * 256;
    for (size_t i = (size_t)blockIdx.x * 256 + threadIdx.x; i < total8; i += stride) {
        float4 a = ((const float4*)in)[i * 2];
        float4 b = ((const float4*)in)[i * 2 + 1];
        bf16x8 v;
        v[0] = (short)f2bf(a.x); v[1] = (short)f2bf(a.y);
        v[2] = (short)f2bf(a.z); v[3] = (short)f2bf(a.w);
        v[4] = (short)f2bf(b.x); v[5] = (short)f2bf(b.y);
        v[6] = (short)f2bf(b.z); v[7] = (short)f2bf(b.w);
        ((bf16x8*)out)[i] = v;
    }
}

// ---------------------------------------------------------------------------
// Rulebook keyed by bucket b = j*4 + k.  ent[pos] = plain src index.
// off doubles as cnt (scan runs in place).
// ---------------------------------------------------------------------------
__global__ __launch_bounds__(256) void count_kernel(
    const int* __restrict__ out_idx, const int* __restrict__ mask,
    int* __restrict__ cnt, int n)
{
    int i = blockIdx.x * 256 + threadIdx.x;
    if (i >= n) return;
    int k = blockIdx.y;
    size_t s = (size_t)k * n + i;
    if (mask[s]) atomicAdd(&cnt[(size_t)out_idx[s] * KOFF + k], 1);
}

__global__ __launch_bounds__(256) void scan_p1(
    const int* __restrict__ in, int* __restrict__ bsum, int L)
{
    __shared__ int red[256];
    int base = blockIdx.x * SCAN_CHUNK;
    int s = 0;
    #pragma unroll
    for (int u = 0; u < 8; ++u) {
        int i = base + u * 256 + threadIdx.x;
        if (i < L) s += in[i];
    }
    red[threadIdx.x] = s;
    __syncthreads();
    for (int d = 128; d > 0; d >>= 1) {
        if (threadIdx.x < d) red[threadIdx.x] += red[threadIdx.x + d];
        __syncthreads();
    }
    if (threadIdx.x == 0) bsum[blockIdx.x] = red[0];
}

__global__ __launch_bounds__(1024) void scan_p2(int* __restrict__ bsum, int NB)
{
    __shared__ int s[1024];
    int t = threadIdx.x;
    s[t] = (t < NB) ? bsum[t] : 0;
    __syncthreads();
    for (int d = 1; d < 1024; d <<= 1) {
        int x = s[t];
        if (t >= d) x += s[t - d];
        __syncthreads();
        s[t] = x;
        __syncthreads();
    }
    if (t < NB) bsum[t] = (t == 0) ? 0 : s[t - 1];   // exclusive
}

__global__ __launch_bounds__(256) void scan_p3(
    const int* in, const int* __restrict__ bsum, int* out, int L)
{
    __shared__ int ts[256];
    int t = threadIdx.x;
    int base = blockIdx.x * SCAN_CHUNK + t * 8;
    int v[8]; int s = 0;
    #pragma unroll
    for (int u = 0; u < 8; ++u) {
        int i = base + u;
        v[u] = (i < L) ? in[i] : 0;
        s += v[u];
    }
    ts[t] = s;
    __syncthreads();
    for (int d = 1; d < 256; d <<= 1) {
        int x = ts[t];
        if (t >= d) x += ts[t - d];
        __syncthreads();
        ts[t] = x;
        __syncthreads();
    }
    int pre = bsum[blockIdx.x] + ((t == 0) ? 0 : ts[t - 1]);
    #pragma unroll
    for (int u = 0; u < 8; ++u) {
        int i = base + u;
        if (i < L) { out[i] = pre; pre += v[u]; }
    }
}

__global__ __launch_bounds__(256) void fill_kernel(
    const int* __restrict__ out_idx, const int* __restrict__ in_idx,
    const int* __restrict__ mask, int* __restrict__ off,
    int* __restrict__ ent, int n)
{
    int i = blockIdx.x * 256 + threadIdx.x;
    if (i >= n) return;
    int k = blockIdx.y;
    size_t s = (size_t)k * n + i;
    if (mask[s]) {
        int j = out_idx[s];
        int pos = atomicAdd(&off[(size_t)j * KOFF + k], 1);
        ent[pos] = in_idx[s];
    }
}
// post-fill: off[b] = END of bucket b; start of b = off[b-1] (b=0 -> 0)

// ---------------------------------------------------------------------------
// Conv: block = 64 output rows, 512 threads (8 waves).
//  p0: off slice -> LDS (coalesced)        p1: primary entry per bucket
//  p2: 8 async global_load_lds per wave: one 1024B LDS row per issue,
//      source pre-swizzled per lane (slot c holds src chunk c^(jl&7)),
//      empty buckets read zero page
//  p3: rare duplicate entries added wave-cooperatively (bf16 RMW in LDS)
//  p4: dense 64x512 @ 512x128 MFMA (merged K over 4 offsets)
//  p5: LDS f32 out-tile (reuse As) + fused BN, coalesced store
//  EPI=0: out = bf16(relu(bn(.)))   EPI=1: out = bn(.) + feat (f32)
// ---------------------------------------------------------------------------
template <int EPI>
__global__ __launch_bounds__(NTHR) void conv_kernel(
    const short* __restrict__ Xb, const short* __restrict__ Wt,
    const int* __restrict__ off, const int* __restrict__ ent,
    const char* __restrict__ zpage,
    const float* __restrict__ gamma, const float* __restrict__ beta,
    const float* __restrict__ mean, const float* __restrict__ var,
    const float* __restrict__ feat, void* __restrict__ Yv, int n, int KN)
{
    const int j0 = blockIdx.x * ROWS;
    const int t  = threadIdx.x;

    __shared__ alignas(16) short As[ROWS * 512];        // 64 KB A-tile
    __shared__ int s_off[ROWS * KOFF + 1];              // 257 ints
    __shared__ int s_prim[ROWS * KOFF];                 // 256 ints
    __shared__ alignas(16) float s_scale[CDIM], s_shift[CDIM];

    if (t < CDIM) {
        float sc = gamma[t] * rsqrtf(var[t] + EPS);
        s_scale[t] = sc;
        s_shift[t] = beta[t] - mean[t] * sc;
    }
    // p0: off slice
    if (t < ROWS * KOFF + 1) {
        int idx = j0 * KOFF + t - 1;
        int v = 0;
        if (idx >= 0) v = off[idx > KN ? KN : idx];
        s_off[t] = v;
    }
    __syncthreads();

    // p1: primaries
    if (t < ROWS * KOFF) {
        int e0 = s_off[t], e1 = s_off[t + 1];
        s_prim[t] = (e1 > e0) ? ent[e0] : -1;
    }
    __syncthreads();

    const int w    = t >> 6;
    const int lane = t & 63;

    // p2: async DMA gather, 8 rows per wave
    {
        int q = lane >> 4;        // k segment
        int p = lane & 15;        // 16B chunk within segment
        #pragma unroll
        for (int i = 0; i < 8; ++i) {
            int jl = w * 8 + i;
            int sw = jl & 7;
            int prim = s_prim[jl * 4 + q];
            const void* g = (prim >= 0)
                ? (const void*)((const char*)Xb + (size_t)prim * 256 + ((p ^ sw) << 4))
                : (const void*)(zpage + ((p ^ sw) << 4));
            gload_lds16(g, (char*)As + jl * 1024);
        }
    }
    asm volatile("s_waitcnt vmcnt(0)" ::: "memory");
    __syncthreads();

    // p3: duplicate entries (rare), wave-cooperative bf16 RMW
    {
        int lchunk = lane >> 2;                 // LDS chunk within segment
        for (int i = 0; i < 32; ++i) {
            int lb = w * 32 + i;                // wave-uniform bucket
            int e0 = s_off[lb], e1 = s_off[lb + 1];
            if (e1 - e0 < 2) continue;
            int jl = lb >> 2, k = lb & 3, sw = jl & 7;
            int schunk = lchunk ^ sw;           // source chunk this lane owns
            unsigned int* lw = (unsigned int*)As + jl * 256 + (k * 16 + lchunk) * 4 + (lane & 3);
            for (int e = e0 + 1; e < e1; ++e) {
                int src = ent[e];
                unsigned int gv = ((const unsigned int*)Xb)[(size_t)src * 64 + schunk * 4 + (lane & 3)];
                unsigned int lv = *lw;
                float lo = bf2f((unsigned short)(lv & 0xffffu)) + bf2f((unsigned short)(gv & 0xffffu));
                float hi = bf2f((unsigned short)(lv >> 16)) + bf2f((unsigned short)(gv >> 16));
                *lw = (unsigned int)f2bf(lo) | ((unsigned int)f2bf(hi) << 16);
            }
        }
    }
    __syncthreads();

    // p4: MFMA. wave w: cout quarter nq = w&3, m half mh = w>>2
    const int lrow = lane & 15;
    const int g    = lane >> 4;
    const int nq   = w & 3;
    const int mh   = w >> 2;

    f32x4 acc[2][2];
    #pragma unroll
    for (int mt = 0; mt < 2; ++mt)
        #pragma unroll
        for (int nt = 0; nt < 2; ++nt) acc[mt][nt] = (f32x4){0.f, 0.f, 0.f, 0.f};

    #pragma unroll
    for (int ks = 0; ks < 16; ++ks) {
        int k  = ks >> 2;
        int kk = ks & 3;
        const short* Wk = Wt + (size_t)k * CDIM * CDIM + kk * 32 + g * 8;
        bf16x8 b0 = *(const bf16x8*)(Wk + (nq * 32 + lrow) * CDIM);
        bf16x8 b1 = *(const bf16x8*)(Wk + (nq * 32 + 16 + lrow) * CDIM);
        int cb = ks * 4 + g;
        #pragma unroll
        for (int mt = 0; mt < 2; ++mt) {
            int row = mh * 32 + mt * 16 + lrow;
            bf16x8 a = *(const bf16x8*)(As + row * 512 + ((cb ^ (row & 7)) << 3));
            acc[mt][0] = __builtin_amdgcn_mfma_f32_16x16x32_bf16(a, b0, acc[mt][0], 0, 0, 0);
            acc[mt][1] = __builtin_amdgcn_mfma_f32_16x16x32_bf16(a, b1, acc[mt][1], 0, 0, 0);
        }
    }
    __syncthreads();      // all As reads done

    // p5: out-tile (reuse As) + fused BN, coalesced store
    float* Ot = (float*)As;                   // [64][128] f32 = 32 KB
    #pragma unroll
    for (int mt = 0; mt < 2; ++mt)
        #pragma unroll
        for (int nt = 0; nt < 2; ++nt)
            #pragma unroll
            for (int jj = 0; jj < 4; ++jj)
                Ot[(mh * 32 + mt * 16 + g * 4 + jj) * CDIM + nq * 32 + nt * 16 + lrow]
                    = acc[mt][nt][jj];
    __syncthreads();

    #pragma unroll
    for (int u = 0; u < 4; ++u) {
        int idx = u * NTHR + t;               // 0..2047 = 64 rows * 32 float4
        int row = idx >> 5, c4 = idx & 31;
        int grow = j0 + row;
        if (grow < n) {
            float4 x  = ((const float4*)Ot)[idx];
            float4 sc = ((const float4*)s_scale)[c4];
            float4 sh = ((const float4*)s_shift)[c4];
            size_t go = (size_t)grow * 32 + c4;
            if (EPI == 0) {
                ushort4 o;
                o.x = f2bf(fmaxf(x.x * sc.x + sh.x, 0.f));
                o.y = f2bf(fmaxf(x.y * sc.y + sh.y, 0.f));
                o.z = f2bf(fmaxf(x.z * sc.z + sh.z, 0.f));
                o.w = f2bf(fmaxf(x.w * sc.w + sh.w, 0.f));
                ((ushort4*)Yv)[go] = o;
            } else {
                float4 f = ((const float4*)feat)[go];
                float4 r;
                r.x = x.x * sc.x + sh.x + f.x;
                r.y = x.y * sc.y + sh.y + f.y;
                r.z = x.z * sc.z + sh.z + f.z;
                r.w = x.w * sc.w + sh.w + f.w;
                ((float4*)Yv)[go] = r;
            }
        }
    }
}

extern "C" void kernel_launch(void* const* d_in, const int* in_sizes, int n_in,
                              void* d_out, int out_size, void* d_ws, size_t ws_size,
                              hipStream_t stream)
{
    const float* feat   = (const float*)d_in[0];
    const float* W1     = (const float*)d_in[1];
    const float* W2     = (const float*)d_in[2];
    const float* gamma1 = (const float*)d_in[3];
    const float* beta1  = (const float*)d_in[4];
    const float* mean1  = (const float*)d_in[5];
    const float* var1   = (const float*)d_in[6];
    const float* gamma2 = (const float*)d_in[7];
    const float* beta2  = (const float*)d_in[8];
    const float* mean2  = (const float*)d_in[9];
    const float* var2   = (const float*)d_in[10];
    const int* in_idx   = (const int*)d_in[11];
    const int* out_idx  = (const int*)d_in[12];
    const int* mask     = (const int*)d_in[13];

    const int n  = in_sizes[0] / CDIM;     // 500000
    const int KN = KOFF * n;
    const int L  = KN + 1;
    const int NB = (L + SCAN_CHUNK - 1) / SCAN_CHUNK;   // 977 <= 1024
    const size_t nelem = (size_t)n * CDIM;

    auto alignup = [](size_t x) { return (x + 255) & ~(size_t)255; };
    char* p = (char*)d_ws;
    int*   off  = (int*)p;    p += alignup((size_t)L * 4);   // doubles as cnt
    int*   bsum = (int*)p;    p += alignup(4096 * 4);
    int*   ent  = (int*)p;    p += alignup((size_t)KN * 4);
    short* W1t  = (short*)p;  p += alignup((size_t)KOFF * CDIM * CDIM * 2);
    short* W2t  = (short*)p;  p += alignup((size_t)KOFF * CDIM * CDIM * 2);
    char*  zpage = p;         p += 256;
    short* h1b  = (short*)p;                 // n*128 bf16 = 128 MB
    short* fb   = (short*)d_out;             // bf16 feat parks in d_out (dead until conv2)

    // rulebook + conversions
    hipMemsetAsync(off, 0, (size_t)L * 4, stream);
    hipMemsetAsync(zpage, 0, 256, stream);
    wconv_kernel<<<(KOFF * CDIM * CDIM + 255) / 256, 256, 0, stream>>>(W1, W2, W1t, W2t);
    cvt_kernel<<<2048, 256, 0, stream>>>(feat, fb, nelem / 8);
    dim3 cg((n + 255) / 256, KOFF);
    count_kernel<<<cg, 256, 0, stream>>>(out_idx, mask, off, n);
    scan_p1<<<NB, 256, 0, stream>>>(off, bsum, L);
    scan_p2<<<1, 1024, 0, stream>>>(bsum, NB);
    scan_p3<<<NB, 256, 0, stream>>>(off, bsum, off, L);
    fill_kernel<<<cg, 256, 0, stream>>>(out_idx, in_idx, mask, off, ent, n);

    // fused convs
    const int nblk = (n + ROWS - 1) / ROWS;
    conv_kernel<0><<<nblk, NTHR, 0, stream>>>(
        fb, W1t, off, ent, zpage, gamma1, beta1, mean1, var1, nullptr, h1b, n, KN);
    conv_kernel<1><<<nblk, NTHR, 0, stream>>>(
        h1b, W2t, off, ent, zpage, gamma2, beta2, mean2, var2, feat, d_out, n, KN);
}